// Round 1
// baseline (33.604 us; speedup 1.0000x reference)
//
#include <hip/hip_runtime.h>

// Problem constants (from reference)
#define B_   8
#define L_   512
#define D_   512
#define CIN_ 7
#define NSV_ 50
#define GAMMA_ 0.1f

// One block per output row n = b*L + l. 256 threads = 4 waves.
// Phase 1: compute enc_out row (512 dims) -> LDS. Each thread does 2 dims.
// Phase 2: RBF distances to 50 support vectors, wave-parallel.
__global__ __launch_bounds__(256) void fused_model_kernel(
    const float* __restrict__ x_enc,     // [B,L,CIN]
    const float* __restrict__ x_mark,    // [B,L,4]
    const float* __restrict__ W_token,   // [D,CIN,3]
    const float* __restrict__ W_time,    // [D,4]
    const float* __restrict__ sv,        // [NSV,D]
    const float* __restrict__ alphas,    // [NSV]
    const float* __restrict__ bias,      // [CIN]
    float* __restrict__ out)             // [B,L,CIN]
{
    __shared__ float x_lds[D_];
    __shared__ float wpart[4];

    const int n   = blockIdx.x;       // 0..B*L-1
    const int b   = n >> 9;           // n / 512
    const int l   = n & (L_ - 1);
    const int tid = threadIdx.x;

    const int lm1 = (l + L_ - 1) & (L_ - 1);
    const int lp1 = (l + 1) & (L_ - 1);

    // Uniform (block-wide) row pointers — compiler scalarizes these loads.
    const float* xr_m1 = x_enc + (b * L_ + lm1) * CIN_;
    const float* xr_0  = x_enc + (b * L_ + l  ) * CIN_;
    const float* xr_p1 = x_enc + (b * L_ + lp1) * CIN_;
    const float* mk    = x_mark + (b * L_ + l) * 4;

    float xm1[CIN_], x0[CIN_], xp1[CIN_], mkv[4];
#pragma unroll
    for (int c = 0; c < CIN_; ++c) {
        xm1[c] = xr_m1[c];
        x0[c]  = xr_0[c];
        xp1[c] = xr_p1[c];
    }
#pragma unroll
    for (int f = 0; f < 4; ++f) mkv[f] = mk[f];

    const float posf = (float)l;
    const float c1 = -0.01798894603901f;  // -ln(10000)/512

#pragma unroll
    for (int r = 0; r < 2; ++r) {
        const int d  = tid + r * 256;
        const int i2 = d & ~1;            // even base for the sin/cos pair
        const float dv  = expf((float)i2 * c1);
        const float ang = posf * dv;
        float acc = (d & 1) ? cosf(ang) : sinf(ang);

        const float* wt = W_token + d * (CIN_ * 3);
#pragma unroll
        for (int c = 0; c < CIN_; ++c) {
            acc = fmaf(xm1[c], wt[c * 3 + 0], acc);
            acc = fmaf(x0[c],  wt[c * 3 + 1], acc);
            acc = fmaf(xp1[c], wt[c * 3 + 2], acc);
        }
        const float* wtm = W_time + d * 4;
#pragma unroll
        for (int f = 0; f < 4; ++f) acc = fmaf(mkv[f], wtm[f], acc);

        x_lds[d] = acc;
    }
    __syncthreads();

    // Phase 2: RBF vs 50 support vectors. Wave w handles s = w, w+4, ...
    const int wave = tid >> 6;
    const int lane = tid & 63;

    float asum = 0.0f;
    for (int s = wave; s < NSV_; s += 4) {
        const float* svr = sv + s * D_;
        float dist = 0.0f;
#pragma unroll
        for (int j = 0; j < 8; ++j) {
            const int d = lane + j * 64;
            const float df = x_lds[d] - svr[d];
            dist = fmaf(df, df, dist);
        }
        // 64-lane butterfly reduce
#pragma unroll
        for (int off = 32; off > 0; off >>= 1)
            dist += __shfl_xor(dist, off, 64);
        if (lane == 0)
            asum = fmaf(alphas[s], expf(-GAMMA_ * dist), asum);
    }
    if (lane == 0) wpart[wave] = asum;
    __syncthreads();

    if (tid == 0) wpart[0] = wpart[0] + wpart[1] + wpart[2] + wpart[3];
    __syncthreads();

    const float p = wpart[0];
    if (tid < CIN_) out[n * CIN_ + tid] = p + bias[tid];
}

extern "C" void kernel_launch(void* const* d_in, const int* in_sizes, int n_in,
                              void* d_out, int out_size, void* d_ws, size_t ws_size,
                              hipStream_t stream) {
    const float* x_enc      = (const float*)d_in[0];
    const float* x_mark_enc = (const float*)d_in[1];
    // d_in[2] (x_dec) and d_in[3] (x_mark_dec) are unused by the reference.
    const float* W_token    = (const float*)d_in[4];
    const float* W_time     = (const float*)d_in[5];
    const float* sv         = (const float*)d_in[6];
    const float* alphas     = (const float*)d_in[7];
    const float* bias       = (const float*)d_in[8];
    float* out = (float*)d_out;

    dim3 grid(B_ * L_);
    dim3 block(256);
    fused_model_kernel<<<grid, block, 0, stream>>>(
        x_enc, x_mark_enc, W_token, W_time, sv, alphas, bias, out);
}

// Round 2
// 15.998 us; speedup vs baseline: 2.1005x; 2.1005x over previous
//
#include <hip/hip_runtime.h>

#define L_     512
#define GAMMA_ 0.1f

typedef _Float16 h2 __attribute__((ext_vector_type(2)));
typedef _Float16 h4 __attribute__((ext_vector_type(4)));
typedef float f32x4 __attribute__((ext_vector_type(4)));

struct alignas(16) H8 { h2 h[4]; };

#if __has_builtin(__builtin_amdgcn_fdot2)
#define DOT2(a, b, c) __builtin_amdgcn_fdot2((a), (b), (c), false)
#else
__device__ __forceinline__ float DOT2(h2 a, h2 b, float c) {
    return fmaf((float)a.x, (float)b.x, fmaf((float)a.y, (float)b.y, c));
}
#endif

// One block per l (512 blocks). 8 rows (batches) share this l's positional
// embedding, conv window, and the LDS-staged f16 transposed support vectors.
// Phase 3: lane <-> support vector, dist^2 = ||x||^2 + ||s||^2 - 2 x.s via
// v_dot2_f32_f16, no per-SV cross-lane reduction.
__global__ __launch_bounds__(256) void fused_model_kernel(
    const float* __restrict__ x_enc,    // [8,512,7]
    const float* __restrict__ x_mark,   // [8,512,4]
    const float* __restrict__ W_token,  // [512,7,3]
    const float* __restrict__ W_time,   // [512,4]
    const float* __restrict__ sv,       // [50,512]
    const float* __restrict__ alphas,   // [50]
    const float* __restrict__ bias,     // [7]
    float* __restrict__ out)            // [8,512,7]
{
    __shared__ f32x4 svT4[64 * 50];   // f16: [dp8][s] -> 8 halves (51.2 KB)
    __shared__ f32x4 xh4[8 * 64];     // f16: [row][dp8] -> 8 halves (8 KB)
    __shared__ float xin[8 * 3 * 7];  // conv inputs: [b][lr][c]
    __shared__ float xmk[8 * 4];      // time marks:  [b][f]
    __shared__ float snp[4 * 64];     // snorm partials [wave][s]
    __shared__ float res[8];          // per-row SVM sum

    const int t = threadIdx.x;
    const int l = blockIdx.x;

    // ---- stage conv inputs + marks ----
    if (t < 168) {
        int b = t / 21, rem = t % 21, lr = rem / 7, c = rem % 7;
        int gl = (l - 1 + lr) & (L_ - 1);      // circular pad
        xin[t] = x_enc[(b * L_ + gl) * 7 + c];
    }
    if (t < 32) {
        int b = t >> 2, f = t & 3;
        xmk[t] = x_mark[(b * L_ + l) * 4 + f];
    }
    // ---- stage sv transposed as f16: svT[dp8][s][8] ----
    const f32x4* sv4 = (const f32x4*)sv;
#pragma unroll
    for (int k = 0; k < 25; ++k) {
        int u4 = t + (k << 8);                 // float4 index, 6400 total
        int s  = u4 >> 7;                      // sv row
        int d0 = (u4 & 127) << 2;              // dim
        f32x4 g = sv4[u4];
        h4 hv = { (_Float16)g.x, (_Float16)g.y, (_Float16)g.z, (_Float16)g.w };
        *(h4*)((char*)svT4 + ((((d0 >> 3) * 50 + s) << 4) + ((d0 & 7) << 1))) = hv;
    }
    __syncthreads();

    const int wave = t >> 6, lane = t & 63;
    const int sl = lane < 50 ? lane : 49;

    // ---- snorm partials (from the same f16-rounded values) ----
    {
        float ssq = 0.f;
#pragma unroll
        for (int i = 0; i < 16; ++i) {
            H8 s8 = __builtin_bit_cast(H8, svT4[(wave * 16 + i) * 50 + sl]);
            ssq = DOT2(s8.h[0], s8.h[0], ssq);
            ssq = DOT2(s8.h[1], s8.h[1], ssq);
            ssq = DOT2(s8.h[2], s8.h[2], ssq);
            ssq = DOT2(s8.h[3], s8.h[3], ssq);
        }
        snp[(wave << 6) + lane] = ssq;
    }

    // ---- phase 1: embedding. thread t -> dims {t, t+256}, all 8 rows ----
    {
        const int da = t, db = t + 256;
        float w0[21], w1[21], m0[4], m1[4];
#pragma unroll
        for (int j = 0; j < 21; ++j) { w0[j] = W_token[da * 21 + j]; w1[j] = W_token[db * 21 + j]; }
#pragma unroll
        for (int j = 0; j < 4; ++j) { m0[j] = W_time[da * 4 + j]; m1[j] = W_time[db * 4 + j]; }
        const float c1 = -0.017988946039016654f;   // -ln(10000)/512
        const float fl = (float)l;
        float ang0 = fl * expf(c1 * (float)(da & ~1));
        float ang1 = fl * expf(c1 * (float)(db & ~1));
        float pe0 = (da & 1) ? cosf(ang0) : sinf(ang0);
        float pe1 = (db & 1) ? cosf(ang1) : sinf(ang1);
        unsigned short* xh = (unsigned short*)xh4;
        for (int b = 0; b < 8; ++b) {
            float a0 = pe0, a1 = pe1;
#pragma unroll
            for (int c = 0; c < 7; ++c)
#pragma unroll
                for (int k = 0; k < 3; ++k) {
                    float xv = xin[b * 21 + k * 7 + c];
                    a0 = fmaf(w0[c * 3 + k], xv, a0);
                    a1 = fmaf(w1[c * 3 + k], xv, a1);
                }
#pragma unroll
            for (int f = 0; f < 4; ++f) {
                float mv = xmk[b * 4 + f];
                a0 = fmaf(m0[f], mv, a0);
                a1 = fmaf(m1[f], mv, a1);
            }
            _Float16 ha = (_Float16)a0, hb = (_Float16)a1;
            xh[b * 512 + da] = __builtin_bit_cast(unsigned short, ha);
            xh[b * 512 + db] = __builtin_bit_cast(unsigned short, hb);
        }
    }
    __syncthreads();

    // ---- phase 3: lane = SV, wave handles rows {2w, 2w+1} ----
    const float snorm = snp[lane] + snp[64 + lane] + snp[128 + lane] + snp[192 + lane];
    const float alpha = alphas[sl];
    const int r0 = wave * 2, r1 = r0 + 1;

    float xn0, xn1;
    {
        H8 v = __builtin_bit_cast(H8, xh4[(r0 << 6) + lane]);   // lane = dp8 here
        float s = 0.f;
        s = DOT2(v.h[0], v.h[0], s); s = DOT2(v.h[1], v.h[1], s);
        s = DOT2(v.h[2], v.h[2], s); s = DOT2(v.h[3], v.h[3], s);
        xn0 = s;
        H8 u = __builtin_bit_cast(H8, xh4[(r1 << 6) + lane]);
        s = 0.f;
        s = DOT2(u.h[0], u.h[0], s); s = DOT2(u.h[1], u.h[1], s);
        s = DOT2(u.h[2], u.h[2], s); s = DOT2(u.h[3], u.h[3], s);
        xn1 = s;
#pragma unroll
        for (int off = 32; off; off >>= 1) {
            xn0 += __shfl_xor(xn0, off, 64);
            xn1 += __shfl_xor(xn1, off, 64);
        }
    }

    float dot0 = 0.f, dot1 = 0.f;
    const f32x4* sp  = svT4 + sl;
    const f32x4* xp0 = xh4 + (r0 << 6);
    const f32x4* xp1 = xh4 + (r1 << 6);
#pragma unroll 4
    for (int dp8 = 0; dp8 < 64; ++dp8) {
        H8 s8 = __builtin_bit_cast(H8, sp[dp8 * 50]);
        H8 a  = __builtin_bit_cast(H8, xp0[dp8]);
        H8 bb = __builtin_bit_cast(H8, xp1[dp8]);
#pragma unroll
        for (int i = 0; i < 4; ++i) {
            dot0 = DOT2(s8.h[i], a.h[i], dot0);
            dot1 = DOT2(s8.h[i], bb.h[i], dot1);
        }
    }
    float dd0 = xn0 + snorm - 2.f * dot0;
    float dd1 = xn1 + snorm - 2.f * dot1;
    float v0 = alpha * expf(-GAMMA_ * dd0);
    float v1 = alpha * expf(-GAMMA_ * dd1);
    v0 = (lane < 50) ? v0 : 0.f;   // mask BEFORE reduce (lanes >=50 are dup/garbage)
    v1 = (lane < 50) ? v1 : 0.f;
#pragma unroll
    for (int off = 32; off; off >>= 1) {
        v0 += __shfl_xor(v0, off, 64);
        v1 += __shfl_xor(v1, off, 64);
    }
    if (lane == 0) { res[r0] = v0; res[r1] = v1; }
    __syncthreads();

    if (t < 56) {
        int row = t / 7, c = t % 7;
        out[(row * L_ + l) * 7 + c] = res[row] + bias[c];
    }
}

extern "C" void kernel_launch(void* const* d_in, const int* in_sizes, int n_in,
                              void* d_out, int out_size, void* d_ws, size_t ws_size,
                              hipStream_t stream) {
    (void)d_ws; (void)ws_size; (void)in_sizes; (void)n_in;
    const float* x_enc      = (const float*)d_in[0];
    const float* x_mark_enc = (const float*)d_in[1];
    // d_in[2] (x_dec), d_in[3] (x_mark_dec) unused by the reference.
    const float* W_token    = (const float*)d_in[4];
    const float* W_time     = (const float*)d_in[5];
    const float* sv         = (const float*)d_in[6];
    const float* alphas     = (const float*)d_in[7];
    const float* bias       = (const float*)d_in[8];
    float* out = (float*)d_out;

    fused_model_kernel<<<dim3(L_), dim3(256), 0, stream>>>(
        x_enc, x_mark_enc, W_token, W_time, sv, alphas, bias, out);
}

// Round 3
// 13.097 us; speedup vs baseline: 2.5658x; 1.2215x over previous
//
#include <hip/hip_runtime.h>

#define L_     512
#define GAMMA_ 0.1f

typedef _Float16 h2 __attribute__((ext_vector_type(2)));
typedef _Float16 h4 __attribute__((ext_vector_type(4)));
typedef _Float16 h8 __attribute__((ext_vector_type(8)));
typedef float    f32x4 __attribute__((ext_vector_type(4)));

struct alignas(16) H8 { h2 h[4]; };

#if __has_builtin(__builtin_amdgcn_fdot2)
#define DOT2(a, b, c) __builtin_amdgcn_fdot2((a), (b), (c), false)
#else
__device__ __forceinline__ float DOT2(h2 a, h2 b, float c) {
    return fmaf((float)a.x, (float)b.x, fmaf((float)a.y, (float)b.y, c));
}
#endif

// 256 blocks (1 per CU), 256 threads (4 waves). Block owns rows r = il*8+b
// (8 batches x 2 consecutive l). sv staged f16 in MFMA-B layout
// [kblk][sv(64)][8], embedding in MFMA-A layout [kblk][row(16)][8], both
// XOR-swizzled (slot ^= kblk&7) for conflict-free ds_read_b128.
// Wave w computes the 16x16 tile C[16 rows][16 svs] with 16 mfma_16x16x32_f16.
__global__ __launch_bounds__(256) void fused_model_kernel(
    const float* __restrict__ x_enc,    // [8,512,7]
    const float* __restrict__ x_mark,   // [8,512,4]
    const float* __restrict__ W_token,  // [512,7,3]
    const float* __restrict__ W_time,   // [512,4]
    const float* __restrict__ sv,       // [50,512]
    const float* __restrict__ alphas,   // [50]
    const float* __restrict__ bias,     // [7]
    float* __restrict__ out)            // [8,512,7]
{
    __shared__ h8 svB[64 * 64];     // 64 KB  B-frag: [kblk][sv^swz][8]
    __shared__ h8 xA[64 * 16];      // 16 KB  A-frag: [kblk][row^swz][8]
    __shared__ float xin[8 * 4 * 7];  // conv window: [b][j=l0-1+j][c]
    __shared__ float xmk[8 * 2 * 4];  // marks: [b][il][f]
    __shared__ float snL[4 * 64], xnL[4 * 16];
    __shared__ float snF[64], xnF[16], alph[64], part[4 * 16];

    const int t  = threadIdx.x;
    const int l0 = blockIdx.x * 2;

    // ---- stage sv -> f16 B-fragment layout (swizzled) ----
    const f32x4* sv4 = (const f32x4*)sv;
#pragma unroll
    for (int k = 0; k < 25; ++k) {
        int u4 = t + (k << 8);           // float4 index, 50*128 total
        int s  = u4 >> 7;
        int dq = u4 & 127;               // float4 within row
        int kblk = dq >> 1;
        int hoff = (dq & 1) << 3;        // byte offset 0 or 8
        f32x4 g = sv4[u4];
        h4 hv = {(_Float16)g.x, (_Float16)g.y, (_Float16)g.z, (_Float16)g.w};
        int slot = kblk * 64 + (s ^ (kblk & 7));
        *(h4*)((char*)svB + slot * 16 + hoff) = hv;
    }
    // ---- stage conv window + marks ----
    if (t < 224) {
        int b = t / 28, rem = t % 28, j = rem / 7, c = rem % 7;
        int gl = (l0 - 1 + j) & (L_ - 1);
        xin[t] = x_enc[(b * L_ + gl) * 7 + c];
    }
    if (t < 64) {
        int b = t >> 3, il = (t >> 2) & 1, f = t & 3;
        xmk[t] = x_mark[(b * L_ + l0 + il) * 4 + f];
    }
    __syncthreads();

    // ---- phase 1: embedding dims d0=2t, d1=2t+1 for all 16 rows ----
    {
        const int d0 = 2 * t;
        const int kblk = t >> 2;         // d0>>3
        const int hb = (d0 & 7) * 2;     // byte offset in 16B slot
        float w0[21], w1[21], m0[4], m1[4];
        const float* W0 = W_token + d0 * 21;
#pragma unroll
        for (int j = 0; j < 21; ++j) { w0[j] = W0[j]; w1[j] = W0[21 + j]; }
#pragma unroll
        for (int j = 0; j < 4; ++j) { m0[j] = W_time[d0 * 4 + j]; m1[j] = W_time[d0 * 4 + 4 + j]; }
        const float C1 = -0.017988946039016654f;   // -ln(10000)/512
        float dv  = expf(C1 * (float)d0);
        float sn0 = sinf((float)l0 * dv),       cs0 = cosf((float)l0 * dv);
        float sn1 = sinf((float)(l0 + 1) * dv), cs1 = cosf((float)(l0 + 1) * dv);
        int slotbase = kblk * 16;
        int swz = kblk & 7;
#pragma unroll
        for (int r = 0; r < 16; ++r) {
            int b = r & 7, il = r >> 3;
            float a0 = il ? sn1 : sn0;
            float a1 = il ? cs1 : cs0;
            const float* xi = xin + b * 28 + il * 7;
#pragma unroll
            for (int c = 0; c < 7; ++c)
#pragma unroll
                for (int kk = 0; kk < 3; ++kk) {
                    float xv = xi[kk * 7 + c];
                    a0 = fmaf(w0[c * 3 + kk], xv, a0);
                    a1 = fmaf(w1[c * 3 + kk], xv, a1);
                }
#pragma unroll
            for (int f = 0; f < 4; ++f) {
                float mv = xmk[(b * 2 + il) * 4 + f];
                a0 = fmaf(m0[f], mv, a0);
                a1 = fmaf(m1[f], mv, a1);
            }
            h2 hp = {(_Float16)a0, (_Float16)a1};
            *(h2*)((char*)xA + (slotbase + (r ^ swz)) * 16 + hb) = hp;
        }
    }
    __syncthreads();

    const int w = t >> 6, lane = t & 63;
    const int g = lane >> 4, q = lane & 15;

    // ---- MFMA: wave w -> C[16 rows][svs 16w..16w+15], K=512 ----
    f32x4 acc = {0.f, 0.f, 0.f, 0.f};
#pragma unroll
    for (int ks = 0; ks < 16; ++ks) {
        int kblk = ks * 4 + g;
        h8 av = xA[kblk * 16 + (q ^ (kblk & 7))];
        h8 bv = svB[kblk * 64 + ((w * 16 + q) ^ (kblk & 7))];
        acc = __builtin_amdgcn_mfma_f32_16x16x32_f16(av, bv, acc, 0, 0, 0);
    }

    // ---- snorm partials: wave w covers kblk 16w..16w+15, lane = sv ----
    {
        float ssq = 0.f;
#pragma unroll
        for (int i = 0; i < 16; ++i) {
            int kblk = w * 16 + i;
            H8 v = __builtin_bit_cast(H8, svB[kblk * 64 + (lane ^ (kblk & 7))]);
            ssq = DOT2(v.h[0], v.h[0], ssq);
            ssq = DOT2(v.h[1], v.h[1], ssq);
            ssq = DOT2(v.h[2], v.h[2], ssq);
            ssq = DOT2(v.h[3], v.h[3], ssq);
        }
        snL[w * 64 + lane] = ssq;
    }
    // ---- xnorm partials ----
    {
        float xsq = 0.f;
#pragma unroll
        for (int i = 0; i < 4; ++i) {
            int kblk = w * 16 + g * 4 + i;
            H8 v = __builtin_bit_cast(H8, xA[kblk * 16 + (q ^ (kblk & 7))]);
            xsq = DOT2(v.h[0], v.h[0], xsq);
            xsq = DOT2(v.h[1], v.h[1], xsq);
            xsq = DOT2(v.h[2], v.h[2], xsq);
            xsq = DOT2(v.h[3], v.h[3], xsq);
        }
        xsq += __shfl_xor(xsq, 16, 64);
        xsq += __shfl_xor(xsq, 32, 64);
        if (g == 0) xnL[w * 16 + q] = xsq;
    }
    __syncthreads();

    if (t < 64) snF[t] = snL[t] + snL[64 + t] + snL[128 + t] + snL[192 + t];
    else if (t < 80) { int r = t - 64; xnF[r] = xnL[r] + xnL[16 + r] + xnL[32 + r] + xnL[48 + r]; }
    else if (t < 144) { int s = t - 80; alph[s] = (s < 50) ? alphas[s] : 0.f; }
    __syncthreads();

    // ---- epilogue: dist^2 -> alpha*exp -> row-sum over 16 svs ----
    {
        int s = w * 16 + q;
        float al = alph[s];
        float sn = snF[s];
        bool valid = (s < 50);
        float vals[4];
#pragma unroll
        for (int i = 0; i < 4; ++i) {
            int row = g * 4 + i;
            float d2 = xnF[row] + sn - 2.f * acc[i];
            float v = al * expf(-GAMMA_ * d2);
            vals[i] = valid ? v : 0.f;
#pragma unroll
            for (int off = 1; off < 16; off <<= 1)
                vals[i] += __shfl_xor(vals[i], off, 64);
        }
        if (q == 0) {
#pragma unroll
            for (int i = 0; i < 4; ++i) part[w * 16 + g * 4 + i] = vals[i];
        }
    }
    __syncthreads();

    if (t < 112) {
        int r = t / 7, c = t % 7;
        int b = r & 7, il = r >> 3;
        out[(b * L_ + l0 + il) * 7 + c] =
            part[r] + part[16 + r] + part[32 + r] + part[48 + r] + bias[c];
    }
}

extern "C" void kernel_launch(void* const* d_in, const int* in_sizes, int n_in,
                              void* d_out, int out_size, void* d_ws, size_t ws_size,
                              hipStream_t stream) {
    (void)d_ws; (void)ws_size; (void)in_sizes; (void)n_in;
    const float* x_enc      = (const float*)d_in[0];
    const float* x_mark_enc = (const float*)d_in[1];
    // d_in[2] (x_dec), d_in[3] (x_mark_dec) unused by the reference.
    const float* W_token    = (const float*)d_in[4];
    const float* W_time     = (const float*)d_in[5];
    const float* sv         = (const float*)d_in[6];
    const float* alphas     = (const float*)d_in[7];
    const float* bias       = (const float*)d_in[8];
    float* out = (float*)d_out;

    fused_model_kernel<<<dim3(L_ / 2), dim3(256), 0, stream>>>(
        x_enc, x_mark_enc, W_token, W_time, sv, alphas, bias, out);
}